// Round 1
// 84.148 us; speedup vs baseline: 1.0091x; 1.0091x over previous
//
#include <hip/hip_runtime.h>

#define NPTS  8192
#define BATCH 4

typedef short  bf8    __attribute__((ext_vector_type(8)));   // 8 bf16 = 4 VGPRs
typedef float  f32x16 __attribute__((ext_vector_type(16)));
typedef float  v2f    __attribute__((ext_vector_type(2)));

__device__ inline unsigned short bf16_rne(float x) {
    unsigned u = __float_as_uint(x);
    unsigned r = (u + 0x7FFFu + ((u >> 16) & 1u)) >> 16;   // round-nearest-even
    return (unsigned short)r;
}
__device__ inline float bf16_to_f(unsigned short h) {
    return __uint_as_float(((unsigned)h) << 16);
}
// Order-preserving float<->uint encode so atomicMax(uint) == float max.
__device__ inline unsigned fenc(float x) {
    unsigned b = __float_as_uint(x);
    return (b & 0x80000000u) ? ~b : (b | 0x80000000u);
}
__device__ inline float fdec(unsigned k) {
    unsigned b = (k & 0x80000000u) ? (k ^ 0x80000000u) : ~k;
    return __uint_as_float(b);
}
// DPP lane-move (VALU-only, no LDS). CTRL is a template param (must be ICE).
template <int CTRL>
__device__ inline float dpp_mov(float x) {
    int i = __float_as_int(x);
    int r = __builtin_amdgcn_update_dpp(i, i, CTRL, 0xF, 0xF, false);
    return __int_as_float(r);
}
// Balanced 16->1 max tree; clang fuses fmax chains into v_max3_f32.
__device__ inline float redmax16(f32x16 v) {
    float a = fmaxf(v[0], v[1]),  b = fmaxf(v[2], v[3]);
    float c = fmaxf(v[4], v[5]),  d = fmaxf(v[6], v[7]);
    float e = fmaxf(v[8], v[9]),  f = fmaxf(v[10], v[11]);
    float g = fmaxf(v[12], v[13]), h = fmaxf(v[14], v[15]);
    float ab = fmaxf(a, b), cd = fmaxf(c, d);
    float ef = fmaxf(e, f), gh = fmaxf(g, h);
    return fmaxf(fmaxf(ab, cd), fmaxf(ef, gh));
}

// ============================================================================
// MFMA path: v_mfma_f32_32x32x16_bf16, layouts VERIFIED end-to-end (R8-R13
// absmax 0.0). ||s-d||^2 = -2*(s.d + w_s + w_d), w_p = -0.5*||p||^2.
// K-slots (16): A = [xh yh zh xl yl zl xh yh | zh 1 1 wh wl 0 0 0]
//               B = [xh yh zh xh yh zh xl yl | zl wh wl 1 1 0 0 0]
//   => C[n,m] = s.d (split-bf16) + w_s + w_d;  dist = max(-2C, 0).
// A/B: point = lane&31, k = (lane>>5)*8 + j. C/D: col = lane&31,
// row = (reg&3) + 8*(reg>>2) + 4*(lane>>5).
//
// R16 (this round): SINGLE-PASS merged fold. Previously two passes each
// computed the same 8192x8192 matrix (transposed) so both reductions were
// row-reductions — 2x the MFMA/ds_read work. Now each tile is computed once:
//   rows  -> rmax regs (as before, v_max3), DPP epilogue -> seg[f-side]
//   cols  -> per-d in-lane 16->1 tree, lane halves merged by ds_max_u32
//            (fenc) into colacc[1024]; block epilogue -> seg[f_-side].
// Liveness discipline (R8/R14 spill lesson): fold d00/d01 to scalars BEFORE
// d10/d11 issue; two coarse sched_barrier(0)/iter cap live d's at 2 (32 VGPR)
// so the 128-VGPR budget (4 waves/SIMD) holds.
// Timing budget: ~42us harness ws-fill (81% HBM peak, untouchable) + pack/
// finalize/launch ~13us + main (MFMA floor now 3.4us, VALU ~5us).
// ============================================================================

__global__ void pack_mfma(const float* __restrict__ f, const float* __restrict__ f_,
                          bf8* __restrict__ fA, bf8* __restrict__ gB,
                          unsigned* __restrict__ seg, float* __restrict__ out) {
    int j = blockIdx.x * blockDim.x + threadIdx.x;   // 0..65535
    if (j == 0) out[0] = 0.0f;                       // d_out poisoned 0xAA
    seg[j] = 0u;                                     // < fenc of any real value
    int cloud = j >> 15;                             // uniform per 256-thr block
    int idx   = j & 32767;                           // b*8192 + p
    const float* src = cloud ? f_ : f;
    float x = src[idx * 3 + 0], y = src[idx * 3 + 1], z = src[idx * 3 + 2];
    float w = -0.5f * (x * x + y * y + z * z);
    unsigned short xh = bf16_rne(x), yh = bf16_rne(y), zh = bf16_rne(z);
    unsigned short xl = bf16_rne(x - bf16_to_f(xh));
    unsigned short yl = bf16_rne(y - bf16_to_f(yh));
    unsigned short zl = bf16_rne(z - bf16_to_f(zh));
    unsigned short wh = bf16_rne(w);
    unsigned short wl = bf16_rne(w - bf16_to_f(wh));
    const short ONE = (short)0x3F80;                 // bf16 1.0

    int b = idx >> 13, p = idx & 8191;
    int t = p >> 5, li = p & 31;                     // 32-point tiles
    size_t base = ((size_t)(b * 256 + t)) * 64;
    if (cloud == 0) {                                // f: A-role only (rows)
        bf8 A0, A1;
        A0[0]=(short)xh; A0[1]=(short)yh; A0[2]=(short)zh; A0[3]=(short)xl;
        A0[4]=(short)yl; A0[5]=(short)zl; A0[6]=(short)xh; A0[7]=(short)yh;
        A1[0]=(short)zh; A1[1]=ONE;       A1[2]=ONE;       A1[3]=(short)wh;
        A1[4]=(short)wl; A1[5]=0;         A1[6]=0;         A1[7]=0;
        fA[base + li]      = A0;                     // khalf 0
        fA[base + 32 + li] = A1;                     // khalf 1
    } else {                                         // f_: B-role only (cols)
        bf8 B0, B1;
        B0[0]=(short)xh; B0[1]=(short)yh; B0[2]=(short)zh; B0[3]=(short)xh;
        B0[4]=(short)yh; B0[5]=(short)zh; B0[6]=(short)xl; B0[7]=(short)yl;
        B1[0]=(short)zl; B1[1]=(short)wh; B1[2]=(short)wl; B1[3]=ONE;
        B1[4]=ONE;       B1[5]=0;         B1[6]=0;         B1[7]=0;
        gB[base + li]      = B0;
        gB[base + 32 + li] = B1;
    }
}

// 512 blocks x 512 thr (8 waves). Block = (b, nblk: 512 rows, mseg: 1024 m
// staged once in 32 KB LDS). Wave holds 2 n-tiles. Per pair-iter: 2
// prefetched ds_read_b128, 4 MFMA(32x32x16), 32 v_max3 row-fold, 2x(16->1)
// col trees + 2 ds_max_u32. Epilogues: DPP rows -> seg[f]; colacc -> seg[f_].
__global__ __launch_bounds__(512, 4) void chamfer_mfma(
        const bf8* __restrict__ fA, const bf8* __restrict__ gB,
        unsigned* __restrict__ seg) {
    __shared__ bf8 lbs[2048];                        // 32 m-tiles = 32 KB
    __shared__ unsigned colacc[1024];                // fenc col-max, 4 KB

    int tid  = threadIdx.x;
    int wv   = tid >> 6, lane = tid & 63;
    int bx   = blockIdx.x;                           // [0, 512)
    int mseg = bx & 7;                               // 8 x 1024-m segments
    int nblk = (bx >> 3) & 15;                       // 16 x 512-row blocks
    int b    = bx >> 7;                              // batch

    // This wave's 2 n-tiles (64 rows) — load first, overlaps with staging.
    bf8 a[2];
    f32x16 rmax[2];
    int nt_loc = nblk * 16 + wv * 2;                 // tile idx within batch
#pragma unroll
    for (int s = 0; s < 2; ++s) {
        a[s] = fA[(size_t)(b * 256 + nt_loc + s) * 64 + lane];
        rmax[s] = (f32x16)(-3.0e38f);
    }

    // Stage 32 B-tiles (1024 m-points): 4x 16B/thread; init col accumulator.
    const bf8* __restrict__ bp = gB + ((size_t)(b * 256 + mseg * 32)) * 64;
#pragma unroll
    for (int k = 0; k < 4; ++k) lbs[k * 512 + tid] = bp[k * 512 + tid];
    colacc[tid]       = 0u;                          // 0 < fenc(any real)
    colacc[tid + 512] = 0u;
    __syncthreads();

    f32x16 zc = (f32x16)(0.0f);
    unsigned* cp = &colacc[lane & 31];               // lanes l, l+32 share col
    bf8 qa = lbs[lane];
    bf8 qb = lbs[64 + lane];
#pragma unroll 2
    for (int i = 0; i < 16; ++i) {
        int ip = (i + 1) & 15;                       // wrap: last is harmless
        bf8 na = lbs[ip * 128 + lane];
        bf8 nb = lbs[ip * 128 + 64 + lane];
        // --- window 1: a[0] pair; fold to scalars so d00/d01 die here ---
        f32x16 d00 = __builtin_amdgcn_mfma_f32_32x32x16_bf16(a[0], qa, zc, 0, 0, 0);
        f32x16 d01 = __builtin_amdgcn_mfma_f32_32x32x16_bf16(a[0], qb, zc, 0, 0, 0);
        rmax[0] = __builtin_elementwise_max(
                      __builtin_elementwise_max(rmax[0], d00), d01);  // v_max3
        float t00 = redmax16(d00);                   // col partial, tile 2i
        float t01 = redmax16(d01);                   // col partial, tile 2i+1
        __builtin_amdgcn_sched_barrier(0);           // cap live d's at 2
        // --- window 2: a[1] pair; finish col folds; LDS atomic merge ---
        f32x16 d10 = __builtin_amdgcn_mfma_f32_32x32x16_bf16(a[1], qa, zc, 0, 0, 0);
        f32x16 d11 = __builtin_amdgcn_mfma_f32_32x32x16_bf16(a[1], qb, zc, 0, 0, 0);
        rmax[1] = __builtin_elementwise_max(
                      __builtin_elementwise_max(rmax[1], d10), d11);
        atomicMax(cp + i * 64,      fenc(fmaxf(t00, redmax16(d10))));  // ds_max
        atomicMax(cp + i * 64 + 32, fenc(fmaxf(t01, redmax16(d11))));
        __builtin_amdgcn_sched_barrier(0);
        qa = na; qb = nb;
    }

    // Row-max across 32 cols — DPP (VALU-only, no LDS):
    // steps 1-4 leave the row16 max in all lanes of the row; row_bcast15
    // folds row k into row k+1 -> group max in lanes 16-31 / 48-63.
#pragma unroll
    for (int s = 0; s < 2; ++s) {
#pragma unroll
        for (int r = 0; r < 16; ++r) {
            float x = rmax[s][r];
            x = fmaxf(x, dpp_mov<0xB1>(x));          // quad_perm [1,0,3,2]
            x = fmaxf(x, dpp_mov<0x4E>(x));          // quad_perm [2,3,0,1]
            x = fmaxf(x, dpp_mov<0x124>(x));         // row_ror:4
            x = fmaxf(x, dpp_mov<0x128>(x));         // row_ror:8
            x = fmaxf(x, dpp_mov<0x142>(x));         // row_bcast15
            rmax[s][r] = x;
        }
    }

    // C/D row = (reg&3) + 8*(reg>>2) + 4*(lane>>5); lanes 16 and 48 hold the
    // folded group max (row_bcast15 lands row k's max in row k+1).
    if ((lane & 31) == 16) {
        int rbase = (lane >> 5) * 4;
        unsigned* sg = seg + (size_t)b * NPTS;       // f-side
#pragma unroll
        for (int s = 0; s < 2; ++s) {
            int n0 = (nt_loc + s) * 32;
#pragma unroll
            for (int r = 0; r < 16; ++r) {
                int row = (r & 3) + 8 * (r >> 2) + rbase;
                atomicMax(&sg[n0 + row], fenc(rmax[s][r]));
            }
        }
    }

    // Col epilogue: all ds_max done -> merge block's 1024-m range into global.
    __syncthreads();
    {
        unsigned* sg = seg + (size_t)(4 + b) * NPTS + mseg * 1024;  // f_-side
        atomicMax(&sg[tid],       colacc[tid]);
        atomicMax(&sg[tid + 512], colacc[tid + 512]);
    }
}

__global__ __launch_bounds__(1024) void finalize_mfma(
        const unsigned* __restrict__ seg, float* __restrict__ out) {
    __shared__ float partial[16];
    int j = blockIdx.x * 1024 + threadIdx.x;         // (side*4+b)*8192 + n
    float emax = fdec(seg[j]);
    float dist = fmaxf(-2.0f * emax, 0.0f);          // C = s.d + w_s + w_d
    for (int off = 32; off > 0; off >>= 1)
        dist += __shfl_down(dist, off, 64);
    int lane = threadIdx.x & 63, wv = threadIdx.x >> 6;
    if (lane == 0) partial[wv] = dist;
    __syncthreads();
    if (threadIdx.x < 16) {
        float s = partial[threadIdx.x];
        for (int off = 8; off > 0; off >>= 1)
            s += __shfl_down(s, off, 64);
        if (threadIdx.x == 0) atomicAdd(out, s * (1.0f / 32768.0f));
    }
}

// ============================================================================
// Fallback 1 (ws >= 3MB): verified R4 packed-fp32 path (45.7 us main).
// ============================================================================

__global__ void pack_pk(const float* __restrict__ f, const float* __restrict__ f_,
                        float4* __restrict__ pk, float* __restrict__ prf,
                        float* __restrict__ out) {
    int j = blockIdx.x * blockDim.x + threadIdx.x;
    if (j == 0) out[0] = 0.0f;
    const float* src = (j >= 32768) ? f_ : f;
    int idx = j & 32767;
    float x = src[idx * 3 + 0], y = src[idx * 3 + 1], z = src[idx * 3 + 2];
    float w = -0.5f * (x * x + y * y + z * z);
    pk[j] = make_float4(x, y, z, w);
    int  slot = j & 1;
    long base = (long)(j >> 1) * 8;
    prf[base + 0 + slot] = x;
    prf[base + 2 + slot] = y;
    prf[base + 4 + slot] = z;
    prf[base + 6 + slot] = w;
}

__global__ __launch_bounds__(512, 8) void chamfer_pk(
        const float4* __restrict__ pk, const float4* __restrict__ pr,
        float* __restrict__ seg) {
    __shared__ float red[8][256];
    int tid  = threadIdx.x;
    int wv   = __builtin_amdgcn_readfirstlane(tid >> 6);
    int lane = tid & 63;
    int bx   = blockIdx.x;
    int tile = bx & 31;
    int b    = (bx >> 5) & 3;
    int dir  = (bx >> 7) & 1;
    int mq   = bx >> 8;

    const float4* __restrict__ A = pk + ((size_t)dir * BATCH + b) * NPTS;
    int n_base = tile * 256;
    v2f px[4], py[4], pz[4], e2[4];
#pragma unroll
    for (int r = 0; r < 4; ++r) {
        float4 p = A[n_base + lane + 64 * r];
        px[r] = (v2f){p.x, p.x};
        py[r] = (v2f){p.y, p.y};
        pz[r] = (v2f){p.z, p.z};
        e2[r] = (v2f){-1e30f, -1e30f};
    }
    int sb_m = (1 - dir) * BATCH + b;
    const float4* __restrict__ mp =
        pr + ((size_t)sb_m * 4096 + mq * 1024 + wv * 128) * 2;

    for (int i = 0; i < 128; i += 4) {
#pragma unroll
        for (int u = 0; u < 4; ++u) {
            float4 qa = mp[(i + u) * 2 + 0];
            float4 qb = mp[(i + u) * 2 + 1];
            v2f qx = (v2f){qa.x, qa.y};
            v2f qy = (v2f){qa.z, qa.w};
            v2f qz = (v2f){qb.x, qb.y};
            v2f qw = (v2f){qb.z, qb.w};
#pragma unroll
            for (int r = 0; r < 4; ++r) {
                v2f c = __builtin_elementwise_fma(px[r], qx, qw);
                c = __builtin_elementwise_fma(py[r], qy, c);
                c = __builtin_elementwise_fma(pz[r], qz, c);
                e2[r] = __builtin_elementwise_max(e2[r], c);
            }
        }
    }
#pragma unroll
    for (int r = 0; r < 4; ++r)
        red[wv][lane + 64 * r] = fmaxf(e2[r].x, e2[r].y);
    __syncthreads();
    if (tid < 256) {
        float emax = red[0][tid];
#pragma unroll
        for (int ww = 1; ww < 8; ++ww) emax = fmaxf(emax, red[ww][tid]);
        seg[mq * (2 * BATCH * NPTS) + dir * (BATCH * NPTS) + b * NPTS
            + n_base + tid] = emax;
    }
}

__global__ __launch_bounds__(1024) void finalize_pk(
        const float4* __restrict__ pk, const float* __restrict__ seg,
        float* __restrict__ out) {
    __shared__ float partial[16];
    int j = blockIdx.x * 1024 + threadIdx.x;
    float emax = seg[j];
#pragma unroll
    for (int q = 1; q < 4; ++q) emax = fmaxf(emax, seg[q * 65536 + j]);
    float dist = fmaxf(-2.0f * (emax + pk[j].w), 0.0f);
    for (int off = 32; off > 0; off >>= 1)
        dist += __shfl_down(dist, off, 64);
    int lane = threadIdx.x & 63, wv = threadIdx.x >> 6;
    if (lane == 0) partial[wv] = dist;
    __syncthreads();
    if (threadIdx.x < 16) {
        float s = partial[threadIdx.x];
        for (int off = 8; off > 0; off >>= 1)
            s += __shfl_down(s, off, 64);
        if (threadIdx.x == 0) atomicAdd(out, s * (1.0f / 32768.0f));
    }
}

// ============================================================================
// Fallback 2 (no ws): verified R2 kernel.
// ============================================================================

__global__ void zero_out_kernel(float* __restrict__ out) { out[0] = 0.0f; }

__global__ __launch_bounds__(1024) void chamfer_fallback(
        const float* __restrict__ f, const float* __restrict__ f_,
        float* __restrict__ out) {
    __shared__ float wlds[NPTS];
    __shared__ float red[16][256];
    __shared__ float partial[4];
    int tid  = threadIdx.x;
    int wv   = __builtin_amdgcn_readfirstlane(tid >> 6);
    int lane = tid & 63;
    int bx   = blockIdx.x;
    int dir  = bx >> 7;
    int b    = (bx >> 5) & 3;
    int tile = bx & 31;
    int n_base = tile * 256;
    const float* __restrict__ A  = dir ? f_ : f;
    const float* __restrict__ Bm = dir ? f  : f_;
    const float* an = A  + (size_t)b * NPTS * 3;
    const float* bm = Bm + (size_t)b * NPTS * 3;
    for (int i = tid; i < NPTS; i += 1024) {
        float x = bm[i * 3 + 0], y = bm[i * 3 + 1], z = bm[i * 3 + 2];
        wlds[i] = -0.5f * (x * x + y * y + z * z);
    }
    float xn[4], yn[4], zn[4];
#pragma unroll
    for (int r = 0; r < 4; ++r) {
        int n = n_base + lane + 64 * r;
        xn[r] = an[n * 3 + 0]; yn[r] = an[n * 3 + 1]; zn[r] = an[n * 3 + 2];
    }
    __syncthreads();
    float e[4];
#pragma unroll
    for (int r = 0; r < 4; ++r) e[r] = -1e30f;
    int m0 = wv * (NPTS / 16);
#pragma unroll 4
    for (int i = 0; i < NPTS / 16; ++i) {
        int m = m0 + i;
        float qx = bm[m * 3 + 0], qy = bm[m * 3 + 1], qz = bm[m * 3 + 2];
        float qw = wlds[m];
#pragma unroll
        for (int r = 0; r < 4; ++r) {
            float c = fmaf(zn[r], qz, fmaf(yn[r], qy, fmaf(xn[r], qx, qw)));
            e[r] = fmaxf(e[r], c);
        }
    }
#pragma unroll
    for (int r = 0; r < 4; ++r) red[wv][lane + 64 * r] = e[r];
    __syncthreads();
    if (tid < 256) {
        float emax = red[0][tid];
#pragma unroll
        for (int ww = 1; ww < 16; ++ww) emax = fmaxf(emax, red[ww][tid]);
        int n = n_base + tid;
        float x = an[n * 3 + 0], y = an[n * 3 + 1], z = an[n * 3 + 2];
        float dist = fmaxf(x * x + y * y + z * z - 2.0f * emax, 0.0f);
        for (int off = 32; off > 0; off >>= 1)
            dist += __shfl_down(dist, off, 64);
        if ((tid & 63) == 0) partial[tid >> 6] = dist;
    }
    __syncthreads();
    if (tid == 0) {
        float s = partial[0] + partial[1] + partial[2] + partial[3];
        atomicAdd(out, s * (1.0f / 32768.0f));
    }
}

extern "C" void kernel_launch(void* const* d_in, const int* in_sizes, int n_in,
                              void* d_out, int out_size, void* d_ws, size_t ws_size,
                              hipStream_t stream) {
    const float* f  = (const float*)d_in[0];
    const float* f_ = (const float*)d_in[1];
    float* out = (float*)d_out;

    const size_t MB = 1048576;
    if (ws_size >= 5 * MB) {
        bf8*      fA  = (bf8*)d_ws;                        // f  as A-role, 1 MB
        bf8*      gB  = (bf8*)((char*)d_ws + 1 * MB);      // f_ as B-role, 1 MB
        unsigned* seg = (unsigned*)((char*)d_ws + 2 * MB); // 256 KB
        pack_mfma<<<256, 256, 0, stream>>>(f, f_, fA, gB, seg, out);
        chamfer_mfma<<<512, 512, 0, stream>>>(fA, gB, seg);
        finalize_mfma<<<64, 1024, 0, stream>>>(seg, out);
    } else if (ws_size >= 3 * MB) {
        float4* pk = (float4*)d_ws;
        float4* pr = (float4*)((char*)d_ws + 1 * MB);
        float*  sg = (float*)((char*)d_ws + 2 * MB);
        pack_pk<<<256, 256, 0, stream>>>(f, f_, pk, (float*)pr, out);
        chamfer_pk<<<1024, 512, 0, stream>>>(pk, pr, sg);
        finalize_pk<<<64, 1024, 0, stream>>>(pk, sg, out);
    } else {
        zero_out_kernel<<<1, 1, 0, stream>>>(out);
        chamfer_fallback<<<256, 1024, 0, stream>>>(f, f_, out);
    }
}

// Round 2
// 79.348 us; speedup vs baseline: 1.0701x; 1.0605x over previous
//
#include <hip/hip_runtime.h>

#define NPTS  8192
#define BATCH 4

typedef short  bf8    __attribute__((ext_vector_type(8)));   // 8 bf16 = 4 VGPRs
typedef float  f32x16 __attribute__((ext_vector_type(16)));
typedef float  v2f    __attribute__((ext_vector_type(2)));

__device__ inline unsigned short bf16_rne(float x) {
    unsigned u = __float_as_uint(x);
    unsigned r = (u + 0x7FFFu + ((u >> 16) & 1u)) >> 16;   // round-nearest-even
    return (unsigned short)r;
}
__device__ inline float bf16_to_f(unsigned short h) {
    return __uint_as_float(((unsigned)h) << 16);
}
// Order-preserving float<->uint encode so max(uint) == float max.
__device__ inline unsigned fenc(float x) {
    unsigned b = __float_as_uint(x);
    return (b & 0x80000000u) ? ~b : (b | 0x80000000u);
}
__device__ inline float fdec(unsigned k) {
    unsigned b = (k & 0x80000000u) ? (k ^ 0x80000000u) : ~k;
    return __uint_as_float(b);
}
// DPP lane-move (VALU-only, no LDS). CTRL is a template param (must be ICE).
template <int CTRL>
__device__ inline float dpp_mov(float x) {
    int i = __float_as_int(x);
    int r = __builtin_amdgcn_update_dpp(i, i, CTRL, 0xF, 0xF, false);
    return __int_as_float(r);
}
// Balanced 16->1 max tree; clang fuses fmax chains into v_max3_f32.
__device__ inline float redmax16(f32x16 v) {
    float a = fmaxf(v[0], v[1]),  b = fmaxf(v[2], v[3]);
    float c = fmaxf(v[4], v[5]),  d = fmaxf(v[6], v[7]);
    float e = fmaxf(v[8], v[9]),  f = fmaxf(v[10], v[11]);
    float g = fmaxf(v[12], v[13]), h = fmaxf(v[14], v[15]);
    float ab = fmaxf(a, b), cd = fmaxf(c, d);
    float ef = fmaxf(e, f), gh = fmaxf(g, h);
    return fmaxf(fmaxf(ab, cd), fmaxf(ef, gh));
}

// ============================================================================
// MFMA path: v_mfma_f32_32x32x16_bf16, layouts VERIFIED end-to-end (R8-R16
// absmax 0.0). ||s-d||^2 = -2*(s.d + w_s + w_d), w_p = -0.5*||p||^2.
// K-slots (16): A = [xh yh zh xl yl zl xh yh | zh 1 1 wh wl 0 0 0]
//               B = [xh yh zh xh yh zh xl yl | zl wh wl 1 1 0 0 0]
//   => C[n,m] = s.d (split-bf16) + w_s + w_d;  dist = max(-2C, 0).
// A/B: point = lane&31, k = (lane>>5)*8 + j. C/D: col = lane&31,
// row = (reg&3) + 8*(reg>>2) + 4*(lane>>5).
//
// R17 (this round): STRUCTURAL fusion. R16's MFMA-halving was perf-neutral
// (84.9 -> 84.1) => the chain is NOT main-loop-pipe-bound. So: fold pack into
// the main kernel (f/f_ are L2-resident; per-block conversion ~300cy), drop
// ALL global atomics (blocks store private partial slices fpart[8]/gpart[16],
// finalize folds them), drop the seg-zero ordering dependency, and make the
// LDS col-merge conflict-free (per-lane-half colacc2[2][1024]: 64 distinct
// addrs/op, 2-way bank alias = free). 3 dispatches/iter -> 2.
// Loop window discipline (R14 spill lesson) kept verbatim: 2 sched_barrier(0)
// per iter cap live d-tiles at 2 so the 128-VGPR budget (4 waves/SIMD) holds.
// ============================================================================

__global__ __launch_bounds__(512, 4) void chamfer_fused(
        const float* __restrict__ f, const float* __restrict__ f_,
        float* __restrict__ fpart, float* __restrict__ gpart,
        float* __restrict__ out) {
    __shared__ bf8 lbs[2048];                        // 32 m-tiles = 32 KB
    __shared__ unsigned colacc2[2048];               // [half][1024] fenc, 8 KB

    int tid  = threadIdx.x;
    int wv   = tid >> 6, lane = tid & 63;
    int bx   = blockIdx.x;                           // [0, 512)
    int mseg = bx & 7;                               // 8 x 1024-m segments
    int nblk = (bx >> 3) & 15;                       // 16 x 512-row blocks
    int b    = bx >> 7;                              // batch

    if (bx == 0 && tid == 0) out[0] = 0.0f;          // d_out poisoned 0xAA

    const short ONE = (short)0x3F80;                 // bf16 1.0

    // ---- A-side: this wave's 2 n-tiles, packed in-register from f --------
    // Lane l holds khalf = l>>5 of point (l&31); lanes l and l+32 read the
    // same 12 B (L1 hit).
    bf8 a[2];
    f32x16 rmax[2];
    int nt_loc = nblk * 16 + wv * 2;                 // tile idx within batch
    const float* __restrict__ fa = f + (size_t)b * NPTS * 3;
#pragma unroll
    for (int s = 0; s < 2; ++s) {
        int p = (nt_loc + s) * 32 + (lane & 31);
        const float* sp = fa + (size_t)p * 3;
        float x = sp[0], y = sp[1], z = sp[2];
        float w = -0.5f * (x * x + y * y + z * z);
        unsigned short xh = bf16_rne(x), yh = bf16_rne(y), zh = bf16_rne(z);
        unsigned short xl = bf16_rne(x - bf16_to_f(xh));
        unsigned short yl = bf16_rne(y - bf16_to_f(yh));
        unsigned short zl = bf16_rne(z - bf16_to_f(zh));
        unsigned short wh = bf16_rne(w);
        unsigned short wl = bf16_rne(w - bf16_to_f(wh));
        bf8 av;
        if (lane < 32) {                             // khalf 0
            av[0]=(short)xh; av[1]=(short)yh; av[2]=(short)zh; av[3]=(short)xl;
            av[4]=(short)yl; av[5]=(short)zl; av[6]=(short)xh; av[7]=(short)yh;
        } else {                                     // khalf 1
            av[0]=(short)zh; av[1]=ONE;       av[2]=ONE;       av[3]=(short)wh;
            av[4]=(short)wl; av[5]=0;         av[6]=0;         av[7]=0;
        }
        a[s] = av;
        rmax[s] = (f32x16)(-3.0e38f);
    }

    // ---- B-side: stage 1024 m-points of f_ into LDS, packed inline -------
    // Thread handles points tid and tid+512 (li = tid&31: conflict-free
    // contiguous ds_write_b128 pattern).
    const float* __restrict__ fb =
        f_ + (size_t)b * NPTS * 3 + (size_t)mseg * 1024 * 3;
#pragma unroll
    for (int h = 0; h < 2; ++h) {
        int p = tid + h * 512;                       // 0..1023
        const float* sp = fb + (size_t)p * 3;
        float x = sp[0], y = sp[1], z = sp[2];
        float w = -0.5f * (x * x + y * y + z * z);
        unsigned short xh = bf16_rne(x), yh = bf16_rne(y), zh = bf16_rne(z);
        unsigned short xl = bf16_rne(x - bf16_to_f(xh));
        unsigned short yl = bf16_rne(y - bf16_to_f(yh));
        unsigned short zl = bf16_rne(z - bf16_to_f(zh));
        unsigned short wh = bf16_rne(w);
        unsigned short wl = bf16_rne(w - bf16_to_f(wh));
        bf8 B0, B1;
        B0[0]=(short)xh; B0[1]=(short)yh; B0[2]=(short)zh; B0[3]=(short)xh;
        B0[4]=(short)yh; B0[5]=(short)zh; B0[6]=(short)xl; B0[7]=(short)yl;
        B1[0]=(short)zl; B1[1]=(short)wh; B1[2]=(short)wl; B1[3]=ONE;
        B1[4]=ONE;       B1[5]=0;         B1[6]=0;         B1[7]=0;
        int t = p >> 5, li = p & 31;
        lbs[t * 64 + li]      = B0;                  // khalf 0
        lbs[t * 64 + 32 + li] = B1;                  // khalf 1
    }
    colacc2[tid]        = 0u;                        // 0 < fenc(any real)
    colacc2[tid + 512]  = 0u;
    colacc2[tid + 1024] = 0u;
    colacc2[tid + 1536] = 0u;
    __syncthreads();

    // ---- main loop: 16 pair-iters, 1-deep ds_read prefetch ----------------
    f32x16 zc = (f32x16)(0.0f);
    int half = lane >> 5, col = lane & 31;
    unsigned* cp = &colacc2[half * 1024 + col];      // conflict-free ds_max
    bf8 qa = lbs[lane];
    bf8 qb = lbs[64 + lane];
#pragma unroll 2
    for (int i = 0; i < 16; ++i) {
        int ip = (i + 1) & 15;                       // wrap: last is harmless
        bf8 na = lbs[ip * 128 + lane];
        bf8 nb = lbs[ip * 128 + 64 + lane];
        // --- window 1: a[0] pair; fold to scalars so d00/d01 die here ---
        f32x16 d00 = __builtin_amdgcn_mfma_f32_32x32x16_bf16(a[0], qa, zc, 0, 0, 0);
        f32x16 d01 = __builtin_amdgcn_mfma_f32_32x32x16_bf16(a[0], qb, zc, 0, 0, 0);
        rmax[0] = __builtin_elementwise_max(
                      __builtin_elementwise_max(rmax[0], d00), d01);  // v_max3
        float r0a = redmax16(d00);                   // col partial, tile 2i
        float r1a = redmax16(d01);                   // col partial, tile 2i+1
        __builtin_amdgcn_sched_barrier(0);           // cap live d's at 2
        // --- window 2: a[1] pair; finish col folds; LDS max merge ---
        f32x16 d10 = __builtin_amdgcn_mfma_f32_32x32x16_bf16(a[1], qa, zc, 0, 0, 0);
        f32x16 d11 = __builtin_amdgcn_mfma_f32_32x32x16_bf16(a[1], qb, zc, 0, 0, 0);
        rmax[1] = __builtin_elementwise_max(
                      __builtin_elementwise_max(rmax[1], d10), d11);
        atomicMax(cp + i * 64,      fenc(fmaxf(r0a, redmax16(d10))));
        atomicMax(cp + i * 64 + 32, fenc(fmaxf(r1a, redmax16(d11))));
        __builtin_amdgcn_sched_barrier(0);
        qa = na; qb = nb;
    }

    // ---- row epilogue: DPP fold (VALU-only), plain stores to fpart --------
    // steps 1-4 leave the row16 max in all lanes of the row; row_bcast15
    // folds row k into row k+1 -> group max in lanes 16-31 / 48-63.
#pragma unroll
    for (int s = 0; s < 2; ++s) {
#pragma unroll
        for (int r = 0; r < 16; ++r) {
            float x = rmax[s][r];
            x = fmaxf(x, dpp_mov<0xB1>(x));          // quad_perm [1,0,3,2]
            x = fmaxf(x, dpp_mov<0x4E>(x));          // quad_perm [2,3,0,1]
            x = fmaxf(x, dpp_mov<0x124>(x));         // row_ror:4
            x = fmaxf(x, dpp_mov<0x128>(x));         // row_ror:8
            x = fmaxf(x, dpp_mov<0x142>(x));         // row_bcast15
            rmax[s][r] = x;
        }
    }
    // C/D row = (reg&3) + 8*(reg>>2) + 4*(lane>>5); lanes 16 and 48 hold the
    // folded group max (row_bcast15 lands row k's max in row k+1).
    if ((lane & 31) == 16) {
        int rbase = (lane >> 5) * 4;
        float* fp = fpart + (size_t)mseg * (BATCH * NPTS) + (size_t)b * NPTS;
#pragma unroll
        for (int s = 0; s < 2; ++s) {
            int n0 = (nt_loc + s) * 32;
#pragma unroll
            for (int r = 0; r < 16; ++r) {
                int row = (r & 3) + 8 * (r >> 2) + rbase;
                fp[n0 + row] = rmax[s][r];           // unique slot, no atomic
            }
        }
    }

    // ---- col epilogue: merge lane-halves, plain stores to gpart -----------
    __syncthreads();
    {
        float* gp = gpart + (size_t)nblk * (BATCH * NPTS) + (size_t)b * NPTS
                    + (size_t)mseg * 1024;
#pragma unroll
        for (int h = 0; h < 2; ++h) {
            int j = tid + h * 512;
            gp[j] = fmaxf(fdec(colacc2[j]), fdec(colacc2[1024 + j]));
        }
    }
}

__global__ __launch_bounds__(1024) void finalize_fused(
        const float* __restrict__ fpart, const float* __restrict__ gpart,
        float* __restrict__ out) {
    __shared__ float partial[16];
    int j = blockIdx.x * 1024 + threadIdx.x;         // (side*4+b)*8192 + n
    float emax;
    if (j < 32768) {                                 // f-side: fold 8 msegs
        emax = fpart[j];
#pragma unroll
        for (int s = 1; s < 8; ++s)
            emax = fmaxf(emax, fpart[s * 32768 + j]);
    } else {                                         // f_-side: fold 16 nblks
        int jj = j - 32768;
        emax = gpart[jj];
#pragma unroll
        for (int t = 1; t < 16; ++t)
            emax = fmaxf(emax, gpart[t * 32768 + jj]);
    }
    float dist = fmaxf(-2.0f * emax, 0.0f);          // C = s.d + w_s + w_d
    for (int off = 32; off > 0; off >>= 1)
        dist += __shfl_down(dist, off, 64);
    int lane = threadIdx.x & 63, wv = threadIdx.x >> 6;
    if (lane == 0) partial[wv] = dist;
    __syncthreads();
    if (threadIdx.x < 16) {
        float s = partial[threadIdx.x];
        for (int off = 8; off > 0; off >>= 1)
            s += __shfl_down(s, off, 64);
        if (threadIdx.x == 0) atomicAdd(out, s * (1.0f / 32768.0f));
    }
}

// ============================================================================
// Fallback 1 (ws >= 3MB): verified R4 packed-fp32 path (45.7 us main).
// ============================================================================

__global__ void pack_pk(const float* __restrict__ f, const float* __restrict__ f_,
                        float4* __restrict__ pk, float* __restrict__ prf,
                        float* __restrict__ out) {
    int j = blockIdx.x * blockDim.x + threadIdx.x;
    if (j == 0) out[0] = 0.0f;
    const float* src = (j >= 32768) ? f_ : f;
    int idx = j & 32767;
    float x = src[idx * 3 + 0], y = src[idx * 3 + 1], z = src[idx * 3 + 2];
    float w = -0.5f * (x * x + y * y + z * z);
    pk[j] = make_float4(x, y, z, w);
    int  slot = j & 1;
    long base = (long)(j >> 1) * 8;
    prf[base + 0 + slot] = x;
    prf[base + 2 + slot] = y;
    prf[base + 4 + slot] = z;
    prf[base + 6 + slot] = w;
}

__global__ __launch_bounds__(512, 8) void chamfer_pk(
        const float4* __restrict__ pk, const float4* __restrict__ pr,
        float* __restrict__ seg) {
    __shared__ float red[8][256];
    int tid  = threadIdx.x;
    int wv   = __builtin_amdgcn_readfirstlane(tid >> 6);
    int lane = tid & 63;
    int bx   = blockIdx.x;
    int tile = bx & 31;
    int b    = (bx >> 5) & 3;
    int dir  = (bx >> 7) & 1;
    int mq   = bx >> 8;

    const float4* __restrict__ A = pk + ((size_t)dir * BATCH + b) * NPTS;
    int n_base = tile * 256;
    v2f px[4], py[4], pz[4], e2[4];
#pragma unroll
    for (int r = 0; r < 4; ++r) {
        float4 p = A[n_base + lane + 64 * r];
        px[r] = (v2f){p.x, p.x};
        py[r] = (v2f){p.y, p.y};
        pz[r] = (v2f){p.z, p.z};
        e2[r] = (v2f){-1e30f, -1e30f};
    }
    int sb_m = (1 - dir) * BATCH + b;
    const float4* __restrict__ mp =
        pr + ((size_t)sb_m * 4096 + mq * 1024 + wv * 128) * 2;

    for (int i = 0; i < 128; i += 4) {
#pragma unroll
        for (int u = 0; u < 4; ++u) {
            float4 qa = mp[(i + u) * 2 + 0];
            float4 qb = mp[(i + u) * 2 + 1];
            v2f qx = (v2f){qa.x, qa.y};
            v2f qy = (v2f){qa.z, qa.w};
            v2f qz = (v2f){qb.x, qb.y};
            v2f qw = (v2f){qb.z, qb.w};
#pragma unroll
            for (int r = 0; r < 4; ++r) {
                v2f c = __builtin_elementwise_fma(px[r], qx, qw);
                c = __builtin_elementwise_fma(py[r], qy, c);
                c = __builtin_elementwise_fma(pz[r], qz, c);
                e2[r] = __builtin_elementwise_max(e2[r], c);
            }
        }
    }
#pragma unroll
    for (int r = 0; r < 4; ++r)
        red[wv][lane + 64 * r] = fmaxf(e2[r].x, e2[r].y);
    __syncthreads();
    if (tid < 256) {
        float emax = red[0][tid];
#pragma unroll
        for (int ww = 1; ww < 8; ++ww) emax = fmaxf(emax, red[ww][tid]);
        seg[mq * (2 * BATCH * NPTS) + dir * (BATCH * NPTS) + b * NPTS
            + n_base + tid] = emax;
    }
}

__global__ __launch_bounds__(1024) void finalize_pk(
        const float4* __restrict__ pk, const float* __restrict__ seg,
        float* __restrict__ out) {
    __shared__ float partial[16];
    int j = blockIdx.x * 1024 + threadIdx.x;
    float emax = seg[j];
#pragma unroll
    for (int q = 1; q < 4; ++q) emax = fmaxf(emax, seg[q * 65536 + j]);
    float dist = fmaxf(-2.0f * (emax + pk[j].w), 0.0f);
    for (int off = 32; off > 0; off >>= 1)
        dist += __shfl_down(dist, off, 64);
    int lane = threadIdx.x & 63, wv = threadIdx.x >> 6;
    if (lane == 0) partial[wv] = dist;
    __syncthreads();
    if (threadIdx.x < 16) {
        float s = partial[threadIdx.x];
        for (int off = 8; off > 0; off >>= 1)
            s += __shfl_down(s, off, 64);
        if (threadIdx.x == 0) atomicAdd(out, s * (1.0f / 32768.0f));
    }
}

// ============================================================================
// Fallback 2 (no ws): verified R2 kernel.
// ============================================================================

__global__ void zero_out_kernel(float* __restrict__ out) { out[0] = 0.0f; }

__global__ __launch_bounds__(1024) void chamfer_fallback(
        const float* __restrict__ f, const float* __restrict__ f_,
        float* __restrict__ out) {
    __shared__ float wlds[NPTS];
    __shared__ float red[16][256];
    __shared__ float partial[4];
    int tid  = threadIdx.x;
    int wv   = __builtin_amdgcn_readfirstlane(tid >> 6);
    int lane = tid & 63;
    int bx   = blockIdx.x;
    int dir  = bx >> 7;
    int b    = (bx >> 5) & 3;
    int tile = bx & 31;
    int n_base = tile * 256;
    const float* __restrict__ A  = dir ? f_ : f;
    const float* __restrict__ Bm = dir ? f  : f_;
    const float* an = A  + (size_t)b * NPTS * 3;
    const float* bm = Bm + (size_t)b * NPTS * 3;
    for (int i = tid; i < NPTS; i += 1024) {
        float x = bm[i * 3 + 0], y = bm[i * 3 + 1], z = bm[i * 3 + 2];
        wlds[i] = -0.5f * (x * x + y * y + z * z);
    }
    float xn[4], yn[4], zn[4];
#pragma unroll
    for (int r = 0; r < 4; ++r) {
        int n = n_base + lane + 64 * r;
        xn[r] = an[n * 3 + 0]; yn[r] = an[n * 3 + 1]; zn[r] = an[n * 3 + 2];
    }
    __syncthreads();
    float e[4];
#pragma unroll
    for (int r = 0; r < 4; ++r) e[r] = -1e30f;
    int m0 = wv * (NPTS / 16);
#pragma unroll 4
    for (int i = 0; i < NPTS / 16; ++i) {
        int m = m0 + i;
        float qx = bm[m * 3 + 0], qy = bm[m * 3 + 1], qz = bm[m * 3 + 2];
        float qw = wlds[m];
#pragma unroll
        for (int r = 0; r < 4; ++r) {
            float c = fmaf(zn[r], qz, fmaf(yn[r], qy, fmaf(xn[r], qx, qw)));
            e[r] = fmaxf(e[r], c);
        }
    }
#pragma unroll
    for (int r = 0; r < 4; ++r) red[wv][lane + 64 * r] = e[r];
    __syncthreads();
    if (tid < 256) {
        float emax = red[0][tid];
#pragma unroll
        for (int ww = 1; ww < 16; ++ww) emax = fmaxf(emax, red[ww][tid]);
        int n = n_base + tid;
        float x = an[n * 3 + 0], y = an[n * 3 + 1], z = an[n * 3 + 2];
        float dist = fmaxf(x * x + y * y + z * z - 2.0f * emax, 0.0f);
        for (int off = 32; off > 0; off >>= 1)
            dist += __shfl_down(dist, off, 64);
        if ((tid & 63) == 0) partial[tid >> 6] = dist;
    }
    __syncthreads();
    if (tid == 0) {
        float s = partial[0] + partial[1] + partial[2] + partial[3];
        atomicAdd(out, s * (1.0f / 32768.0f));
    }
}

extern "C" void kernel_launch(void* const* d_in, const int* in_sizes, int n_in,
                              void* d_out, int out_size, void* d_ws, size_t ws_size,
                              hipStream_t stream) {
    const float* f  = (const float*)d_in[0];
    const float* f_ = (const float*)d_in[1];
    float* out = (float*)d_out;

    const size_t MB = 1048576;
    if (ws_size >= 5 * MB) {
        float* fpart = (float*)d_ws;                       // [8][4*8192] = 1 MB
        float* gpart = (float*)((char*)d_ws + 1 * MB);     // [16][4*8192] = 2 MB
        chamfer_fused<<<512, 512, 0, stream>>>(f, f_, fpart, gpart, out);
        finalize_fused<<<64, 1024, 0, stream>>>(fpart, gpart, out);
    } else if (ws_size >= 3 * MB) {
        float4* pk = (float4*)d_ws;
        float4* pr = (float4*)((char*)d_ws + 1 * MB);
        float*  sg = (float*)((char*)d_ws + 2 * MB);
        pack_pk<<<256, 256, 0, stream>>>(f, f_, pk, (float*)pr, out);
        chamfer_pk<<<1024, 512, 0, stream>>>(pk, pr, sg);
        finalize_pk<<<64, 1024, 0, stream>>>(pk, sg, out);
    } else {
        zero_out_kernel<<<1, 1, 0, stream>>>(out);
        chamfer_fallback<<<256, 1024, 0, stream>>>(f, f_, out);
    }
}